// Round 1
// baseline (467.495 us; speedup 1.0000x reference)
//
#include <hip/hip_runtime.h>

#define BB 512
#define II 1152
#define OO 10
#define DD 16
#define JJ 8
#define OD 160           // OO*DD
#define KK (II*JJ)       // 9216

// s_part config
#define BT 64            // b-tile
#define NBT (BB/BT)      // 8
#define IC 16            // i-chunk
#define NS (II/IC)       // 72
// agree config
#define NB 8             // b-splits
#define BCH (BB/NB)      // 64

// ---------------- transpose x[b][k] -> xT[k][b] ----------------
__global__ __launch_bounds__(256) void k_transpose(const float* __restrict__ x,
                                                   float* __restrict__ xT) {
  __shared__ float tile[32][33];
  int kb = blockIdx.x;            // 288 tiles of k
  int bb = blockIdx.y;            // 16 tiles of b
  int tx = threadIdx.x & 31, ty = threadIdx.x >> 5;  // 32 x 8
  int k0 = kb * 32, b0 = bb * 32;
#pragma unroll
  for (int r = ty; r < 32; r += 8)
    tile[r][tx] = x[(size_t)(b0 + r) * KK + k0 + tx];
  __syncthreads();
#pragma unroll
  for (int r = ty; r < 32; r += 8)
    xT[(size_t)(k0 + r) * BB + b0 + tx] = tile[tx][r];
}

// ---------------- softmax over i (axis 0) per o ----------------
__global__ __launch_bounds__(256) void k_softmax(const float* __restrict__ b_ij,
                                                 float* __restrict__ c) {
  int o = blockIdx.x, t = threadIdx.x;
  __shared__ float buf[II];
  __shared__ float red[4];
  float mx = -1e30f;
  for (int i = t; i < II; i += 256) {
    float val = b_ij[i * OO + o];
    buf[i] = val;
    mx = fmaxf(mx, val);
  }
  for (int off = 32; off; off >>= 1) mx = fmaxf(mx, __shfl_down(mx, off));
  if ((t & 63) == 0) red[t >> 6] = mx;
  __syncthreads();
  mx = fmaxf(fmaxf(red[0], red[1]), fmaxf(red[2], red[3]));
  __syncthreads();
  float sum = 0.f;
  for (int i = t; i < II; i += 256) {
    float e = expf(buf[i] - mx);
    buf[i] = e;
    sum += e;
  }
  for (int off = 32; off; off >>= 1) sum += __shfl_down(sum, off);
  if ((t & 63) == 0) red[t >> 6] = sum;
  __syncthreads();
  sum = red[0] + red[1] + red[2] + red[3];
  float inv = 1.0f / sum;
  for (int i = t; i < II; i += 256) c[i * OO + o] = buf[i] * inv;
}

// ---------------- b update + softmax fused ----------------
__global__ __launch_bounds__(256) void k_bupd_softmax(float* __restrict__ b_ij,
                                                      const float* __restrict__ bp,
                                                      float* __restrict__ c) {
  int o = blockIdx.x, t = threadIdx.x;
  __shared__ float buf[II];
  __shared__ float red[4];
  float mx = -1e30f;
  for (int i = t; i < II; i += 256) {
    float a = 0.f;
#pragma unroll
    for (int nb = 0; nb < NB; ++nb) a += bp[nb * (II * OO) + i * OO + o];
    float val = b_ij[i * OO + o] + a * (1.0f / (float)BB);
    b_ij[i * OO + o] = val;
    buf[i] = val;
    mx = fmaxf(mx, val);
  }
  for (int off = 32; off; off >>= 1) mx = fmaxf(mx, __shfl_down(mx, off));
  if ((t & 63) == 0) red[t >> 6] = mx;
  __syncthreads();
  mx = fmaxf(fmaxf(red[0], red[1]), fmaxf(red[2], red[3]));
  __syncthreads();
  float sum = 0.f;
  for (int i = t; i < II; i += 256) {
    float e = expf(buf[i] - mx);
    buf[i] = e;
    sum += e;
  }
  for (int off = 32; off; off >>= 1) sum += __shfl_down(sum, off);
  if ((t & 63) == 0) red[t >> 6] = sum;
  __syncthreads();
  sum = red[0] + red[1] + red[2] + red[3];
  float inv = 1.0f / sum;
  for (int i = t; i < II; i += 256) c[i * OO + o] = buf[i] * inv;
}

// ---------------- s partials: spart[ch][b][od] ----------------
// block (bt, ch): 64 b's x all 160 od x 16 i's. thread: 4 b x 10 od.
__global__ __launch_bounds__(256) void k_s_part(const float* __restrict__ xT,
                                                const float* __restrict__ W,
                                                const float* __restrict__ c,
                                                float* __restrict__ spart) {
  __shared__ float smem[64 * 164];  // wc uses first 5120; epilogue uses 64x164
  int bt = blockIdx.x;              // 0..7
  int ch = blockIdx.y;              // 0..71
  int b0 = bt * BT;
  int i0 = ch * IC;
  int t = threadIdx.x;
  int bq = t & 15;   // b = b0 + bq*4 + bb
  int og = t >> 4;   // od = og*10 + r
  float acc[4][10];
#pragma unroll
  for (int bb = 0; bb < 4; ++bb)
#pragma unroll
    for (int r = 0; r < 10; ++r) acc[bb][r] = 0.f;

  for (int g = 0; g < 4; ++g) {
    int ig = i0 + g * 4;
    __syncthreads();
    // stage wc = c (.) W for 4 i's: 4*1280 floats
#pragma unroll
    for (int q = 0; q < 5; ++q) {
      int e4 = q * 256 + t;         // float4 index in [0,1280)
      int ii = e4 / 320;
      int rem = e4 - ii * 320;
      int o = rem >> 5;             // 32 float4 per o
      float cv = c[(ig + ii) * OO + o];
      float4 w4 = *(const float4*)&W[(size_t)(ig + ii) * 1280 + rem * 4];
      float4 r4;
      r4.x = w4.x * cv; r4.y = w4.y * cv; r4.z = w4.z * cv; r4.w = w4.w * cv;
      *(float4*)&smem[ii * 1280 + rem * 4] = r4;
    }
    __syncthreads();
#pragma unroll
    for (int ii = 0; ii < 4; ++ii) {
      int i = ig + ii;
      float xr[8][4];
#pragma unroll
      for (int j = 0; j < 8; ++j) {
        float4 q4 = *(const float4*)&xT[(size_t)(i * 8 + j) * BB + b0 + bq * 4];
        xr[j][0] = q4.x; xr[j][1] = q4.y; xr[j][2] = q4.z; xr[j][3] = q4.w;
      }
      const float* wrow = &smem[ii * 1280 + og * 80];
#pragma unroll
      for (int r = 0; r < 10; ++r) {
        float4 w0 = *(const float4*)&wrow[r * 8];
        float4 w1 = *(const float4*)&wrow[r * 8 + 4];
#pragma unroll
        for (int bb = 0; bb < 4; ++bb) {
          float a = acc[bb][r];
          a = fmaf(xr[0][bb], w0.x, a);
          a = fmaf(xr[1][bb], w0.y, a);
          a = fmaf(xr[2][bb], w0.z, a);
          a = fmaf(xr[3][bb], w0.w, a);
          a = fmaf(xr[4][bb], w1.x, a);
          a = fmaf(xr[5][bb], w1.y, a);
          a = fmaf(xr[6][bb], w1.z, a);
          a = fmaf(xr[7][bb], w1.w, a);
          acc[bb][r] = a;
        }
      }
    }
  }
  // epilogue: LDS transpose for coalesced global stores
  __syncthreads();
#pragma unroll
  for (int bb = 0; bb < 4; ++bb)
#pragma unroll
    for (int r = 0; r < 10; ++r)
      smem[(bq * 4 + bb) * 164 + og * 10 + r] = acc[bb][r];
  __syncthreads();
  float* dst = &spart[(size_t)ch * BB * OD + (size_t)b0 * OD];
#pragma unroll
  for (int k2 = 0; k2 < 10; ++k2) {
    int idx = k2 * 256 + t;         // float4 index over 2560
    int row = idx / 40;
    int col4 = idx - row * 40;
    float4 val = *(const float4*)&smem[row * 164 + col4 * 4];
    *(float4*)&dst[row * 160 + col4 * 4] = val;
  }
}

// ---------------- reduce partials + squash ----------------
__global__ __launch_bounds__(256) void k_squash(const float* __restrict__ spart,
                                                float* __restrict__ v) {
  int t = blockIdx.x * 256 + threadIdx.x;  // over B*OD = 81920
  float s = 0.f;
#pragma unroll 8
  for (int ns = 0; ns < NS; ++ns) s += spart[(size_t)ns * (BB * OD) + t];
  float sq = s * s;
  sq += __shfl_xor(sq, 1);
  sq += __shfl_xor(sq, 2);
  sq += __shfl_xor(sq, 4);
  sq += __shfl_xor(sq, 8);
  float scale = sqrtf(sq) / (1.0f + sq);
  v[t] = s * scale;
}

// ---------------- agreement partials: bp[nb][i][o] ----------------
__global__ __launch_bounds__(256) void k_agree(const float* __restrict__ x,
                                               const float* __restrict__ W,
                                               const float* __restrict__ v,
                                               float* __restrict__ bp) {
  int gt = blockIdx.x * 256 + threadIdx.x;  // (nb, i, o, d)
  int d = gt & 15;
  int rest = gt >> 4;          // (nb*II + i)*OO + o
  int o = rest % OO;
  int tmp = rest / OO;         // nb*II + i
  int i = tmp % II;
  int nb = tmp / II;
  const float* wp = &W[(size_t)((i * OO + o) * DD + d) * JJ];
  float4 w0 = *(const float4*)wp;
  float4 w1 = *(const float4*)(wp + 4);
  float acc = 0.f;
  int b0 = nb * BCH;
  for (int b = b0; b < b0 + BCH; ++b) {
    const float* xp = &x[(size_t)(b * II + i) * JJ];
    float4 x0 = *(const float4*)xp;
    float4 x1 = *(const float4*)(xp + 4);
    float u = 0.f;
    u = fmaf(w0.x, x0.x, u);
    u = fmaf(w0.y, x0.y, u);
    u = fmaf(w0.z, x0.z, u);
    u = fmaf(w0.w, x0.w, u);
    u = fmaf(w1.x, x1.x, u);
    u = fmaf(w1.y, x1.y, u);
    u = fmaf(w1.z, x1.z, u);
    u = fmaf(w1.w, x1.w, u);
    acc = fmaf(u, v[(b * OO + o) * DD + d], acc);
  }
  acc += __shfl_xor(acc, 1);
  acc += __shfl_xor(acc, 2);
  acc += __shfl_xor(acc, 4);
  acc += __shfl_xor(acc, 8);
  if (d == 0) bp[nb * (II * OO) + i * OO + o] = acc;
}

extern "C" void kernel_launch(void* const* d_in, const int* in_sizes, int n_in,
                              void* d_out, int out_size, void* d_ws, size_t ws_size,
                              hipStream_t stream) {
  const float* x = (const float*)d_in[0];   // [512][1152][8]
  const float* W = (const float*)d_in[1];   // [1152][10][16][8]
  float* out = (float*)d_out;               // [512][10][16][1] == flat v
  float* ws = (float*)d_ws;

  float* b_ij = ws;                 // 11520
  float* c    = ws + 11520;         // 11520
  float* bp   = ws + 23040;         // 8*11520   = 92160
  float* sp   = ws + 115200;        // 72*81920  = 5898240
  float* xT   = ws + 6013440;       // 9216*512  = 4718592
  float* vv   = ws + 10732032;      // 81920

  hipMemsetAsync(b_ij, 0, 11520 * sizeof(float), stream);
  k_transpose<<<dim3(288, 16), 256, 0, stream>>>(x, xT);
  k_softmax<<<OO, 256, 0, stream>>>(b_ij, c);   // c1 (uniform from zeros)

  for (int it = 0; it < 3; ++it) {
    k_s_part<<<dim3(NBT, NS), 256, 0, stream>>>(xT, W, c, sp);
    k_squash<<<320, 256, 0, stream>>>(sp, it == 2 ? out : vv);
    if (it < 2) {
      k_agree<<<5760, 256, 0, stream>>>(x, W, vv, bp);
      k_bupd_softmax<<<OO, 256, 0, stream>>>(b_ij, bp, c);
    }
  }
}

// Round 2
// 383.755 us; speedup vs baseline: 1.2182x; 1.2182x over previous
//
#include <hip/hip_runtime.h>

#define BB 512
#define II 1152
#define OO 10
#define DD 16
#define JJ 8
#define OD 160           // OO*DD
#define KK (II*JJ)       // 9216

// s_part config
#define BT 64            // b-tile
#define NBT (BB/BT)      // 8
#define IC 16            // i-chunk
#define NS (II/IC)       // 72

// ---------------- transpose x[b][k] -> xT[k][b] ----------------
__global__ __launch_bounds__(256) void k_transpose(const float* __restrict__ x,
                                                   float* __restrict__ xT) {
  __shared__ float tile[32][33];
  int kb = blockIdx.x;            // 288 tiles of k
  int bb = blockIdx.y;            // 16 tiles of b
  int tx = threadIdx.x & 31, ty = threadIdx.x >> 5;  // 32 x 8
  int k0 = kb * 32, b0 = bb * 32;
#pragma unroll
  for (int r = ty; r < 32; r += 8)
    tile[r][tx] = x[(size_t)(b0 + r) * KK + k0 + tx];
  __syncthreads();
#pragma unroll
  for (int r = ty; r < 32; r += 8)
    xT[(size_t)(k0 + r) * BB + b0 + tx] = tile[tx][r];
}

// ---------------- softmax over i (axis 0) per o ----------------
__global__ __launch_bounds__(256) void k_softmax(const float* __restrict__ b_ij,
                                                 float* __restrict__ c) {
  int o = blockIdx.x, t = threadIdx.x;
  __shared__ float buf[II];
  __shared__ float red[4];
  float mx = -1e30f;
  for (int i = t; i < II; i += 256) {
    float val = b_ij[i * OO + o];
    buf[i] = val;
    mx = fmaxf(mx, val);
  }
  for (int off = 32; off; off >>= 1) mx = fmaxf(mx, __shfl_down(mx, off));
  if ((t & 63) == 0) red[t >> 6] = mx;
  __syncthreads();
  mx = fmaxf(fmaxf(red[0], red[1]), fmaxf(red[2], red[3]));
  __syncthreads();
  float sum = 0.f;
  for (int i = t; i < II; i += 256) {
    float e = expf(buf[i] - mx);
    buf[i] = e;
    sum += e;
  }
  for (int off = 32; off; off >>= 1) sum += __shfl_down(sum, off);
  if ((t & 63) == 0) red[t >> 6] = sum;
  __syncthreads();
  sum = red[0] + red[1] + red[2] + red[3];
  float inv = 1.0f / sum;
  for (int i = t; i < II; i += 256) c[i * OO + o] = buf[i] * inv;
}

// ---------------- b update (from agree) + softmax fused ----------------
__global__ __launch_bounds__(256) void k_bupd_softmax(float* __restrict__ b_ij,
                                                      const float* __restrict__ agree,
                                                      float* __restrict__ c) {
  int o = blockIdx.x, t = threadIdx.x;
  __shared__ float buf[II];
  __shared__ float red[4];
  float mx = -1e30f;
  for (int i = t; i < II; i += 256) {
    float val = b_ij[i * OO + o] + agree[i * OO + o];
    b_ij[i * OO + o] = val;
    buf[i] = val;
    mx = fmaxf(mx, val);
  }
  for (int off = 32; off; off >>= 1) mx = fmaxf(mx, __shfl_down(mx, off));
  if ((t & 63) == 0) red[t >> 6] = mx;
  __syncthreads();
  mx = fmaxf(fmaxf(red[0], red[1]), fmaxf(red[2], red[3]));
  __syncthreads();
  float sum = 0.f;
  for (int i = t; i < II; i += 256) {
    float e = expf(buf[i] - mx);
    buf[i] = e;
    sum += e;
  }
  for (int off = 32; off; off >>= 1) sum += __shfl_down(sum, off);
  if ((t & 63) == 0) red[t >> 6] = sum;
  __syncthreads();
  sum = red[0] + red[1] + red[2] + red[3];
  float inv = 1.0f / sum;
  for (int i = t; i < II; i += 256) c[i * OO + o] = buf[i] * inv;
}

// ---------------- s partials: spart[ch][b][od] ----------------
__global__ __launch_bounds__(256) void k_s_part(const float* __restrict__ xT,
                                                const float* __restrict__ W,
                                                const float* __restrict__ c,
                                                float* __restrict__ spart) {
  __shared__ float smem[64 * 164];
  int bt = blockIdx.x;              // 0..7
  int ch = blockIdx.y;              // 0..71
  int b0 = bt * BT;
  int i0 = ch * IC;
  int t = threadIdx.x;
  int bq = t & 15;   // b = b0 + bq*4 + bb
  int og = t >> 4;   // od = og*10 + r
  float acc[4][10];
#pragma unroll
  for (int bb = 0; bb < 4; ++bb)
#pragma unroll
    for (int r = 0; r < 10; ++r) acc[bb][r] = 0.f;

  for (int g = 0; g < 4; ++g) {
    int ig = i0 + g * 4;
    __syncthreads();
#pragma unroll
    for (int q = 0; q < 5; ++q) {
      int e4 = q * 256 + t;         // float4 index in [0,1280)
      int ii = e4 / 320;
      int rem = e4 - ii * 320;
      int o = rem >> 5;             // 32 float4 per o
      float cv = c[(ig + ii) * OO + o];
      float4 w4 = *(const float4*)&W[(size_t)(ig + ii) * 1280 + rem * 4];
      float4 r4;
      r4.x = w4.x * cv; r4.y = w4.y * cv; r4.z = w4.z * cv; r4.w = w4.w * cv;
      *(float4*)&smem[ii * 1280 + rem * 4] = r4;
    }
    __syncthreads();
#pragma unroll
    for (int ii = 0; ii < 4; ++ii) {
      int i = ig + ii;
      float xr[8][4];
#pragma unroll
      for (int j = 0; j < 8; ++j) {
        float4 q4 = *(const float4*)&xT[(size_t)(i * 8 + j) * BB + b0 + bq * 4];
        xr[j][0] = q4.x; xr[j][1] = q4.y; xr[j][2] = q4.z; xr[j][3] = q4.w;
      }
      const float* wrow = &smem[ii * 1280 + og * 80];
#pragma unroll
      for (int r = 0; r < 10; ++r) {
        float4 w0 = *(const float4*)&wrow[r * 8];
        float4 w1 = *(const float4*)&wrow[r * 8 + 4];
#pragma unroll
        for (int bb = 0; bb < 4; ++bb) {
          float a = acc[bb][r];
          a = fmaf(xr[0][bb], w0.x, a);
          a = fmaf(xr[1][bb], w0.y, a);
          a = fmaf(xr[2][bb], w0.z, a);
          a = fmaf(xr[3][bb], w0.w, a);
          a = fmaf(xr[4][bb], w1.x, a);
          a = fmaf(xr[5][bb], w1.y, a);
          a = fmaf(xr[6][bb], w1.z, a);
          a = fmaf(xr[7][bb], w1.w, a);
          acc[bb][r] = a;
        }
      }
    }
  }
  __syncthreads();
#pragma unroll
  for (int bb = 0; bb < 4; ++bb)
#pragma unroll
    for (int r = 0; r < 10; ++r)
      smem[(bq * 4 + bb) * 164 + og * 10 + r] = acc[bb][r];
  __syncthreads();
  float* dst = &spart[(size_t)ch * BB * OD + (size_t)b0 * OD];
#pragma unroll
  for (int k2 = 0; k2 < 10; ++k2) {
    int idx = k2 * 256 + t;
    int row = idx / 40;
    int col4 = idx - row * 40;
    float4 val = *(const float4*)&smem[row * 164 + col4 * 4];
    *(float4*)&dst[row * 160 + col4 * 4] = val;
  }
}

// ---------------- reduce partials + squash ----------------
__global__ __launch_bounds__(256) void k_squash(const float* __restrict__ spart,
                                                float* __restrict__ v) {
  int t = blockIdx.x * 256 + threadIdx.x;  // over B*OD = 81920
  float s = 0.f;
#pragma unroll 8
  for (int ns = 0; ns < NS; ++ns) s += spart[(size_t)ns * (BB * OD) + t];
  float sq = s * s;
  sq += __shfl_xor(sq, 1);
  sq += __shfl_xor(sq, 2);
  sq += __shfl_xor(sq, 4);
  sq += __shfl_xor(sq, 8);
  float scale = sqrtf(sq) / (1.0f + sq);
  v[t] = s * scale;
}

// ---------------- G = xT @ v : Gp[bh][k][od], k in 9216, od in 160 ----------------
// block (kt, bh): 64 k-rows x 160 od, contraction over 256 b's.
__global__ __launch_bounds__(256) void k_G(const float* __restrict__ xT,
                                           const float* __restrict__ v,
                                           float* __restrict__ Gp) {
  __shared__ float smem[64 * 164];  // staging (16x160) + epilogue (64x164)
  int k0 = blockIdx.x * 64;         // 144 tiles
  int bh = blockIdx.y;              // 0..1
  int t = threadIdx.x;
  int kq = t & 15;    // k = k0 + kq*4 + kk
  int og = t >> 4;    // od = og*10 + r
  float acc[4][10];
#pragma unroll
  for (int kk = 0; kk < 4; ++kk)
#pragma unroll
    for (int r = 0; r < 10; ++r) acc[kk][r] = 0.f;

  for (int cch = 0; cch < 16; ++cch) {
    int b0 = bh * 256 + cch * 16;
    __syncthreads();
    // stage v[b0:b0+16][0:160] -> smem (640 float4)
#pragma unroll
    for (int idx = t; idx < 640; idx += 256) {
      int b = idx / 40;
      int q = idx - b * 40;
      *(float4*)&smem[b * 160 + q * 4] = *(const float4*)&v[(size_t)(b0 + b) * 160 + q * 4];
    }
    __syncthreads();
    float xr[4][16];
#pragma unroll
    for (int kk = 0; kk < 4; ++kk) {
      size_t krow = (size_t)(k0 + kq * 4 + kk) * BB + b0;
#pragma unroll
      for (int q = 0; q < 4; ++q) {
        float4 x4 = *(const float4*)&xT[krow + q * 4];
        xr[kk][q * 4 + 0] = x4.x; xr[kk][q * 4 + 1] = x4.y;
        xr[kk][q * 4 + 2] = x4.z; xr[kk][q * 4 + 3] = x4.w;
      }
    }
#pragma unroll
    for (int b = 0; b < 16; ++b) {
      const float* vrow = &smem[b * 160 + og * 10];
#pragma unroll
      for (int r = 0; r < 10; ++r) {
        float vv_ = vrow[r];
        acc[0][r] = fmaf(xr[0][b], vv_, acc[0][r]);
        acc[1][r] = fmaf(xr[1][b], vv_, acc[1][r]);
        acc[2][r] = fmaf(xr[2][b], vv_, acc[2][r]);
        acc[3][r] = fmaf(xr[3][b], vv_, acc[3][r]);
      }
    }
  }
  // epilogue: LDS transpose, coalesced float4 stores
  __syncthreads();
#pragma unroll
  for (int kk = 0; kk < 4; ++kk)
#pragma unroll
    for (int r = 0; r < 10; ++r)
      smem[(kq * 4 + kk) * 164 + og * 10 + r] = acc[kk][r];
  __syncthreads();
  float* dst = &Gp[(size_t)bh * KK * OD + (size_t)k0 * OD];
#pragma unroll
  for (int k2 = 0; k2 < 10; ++k2) {
    int idx = k2 * 256 + t;
    int row = idx / 40;
    int col4 = idx - row * 40;
    float4 val = *(const float4*)&smem[row * 164 + col4 * 4];
    *(float4*)&dst[row * 160 + col4 * 4] = val;
  }
}

// ---------------- agree[i][o] = (1/B) * sum_{j,d} W[i,o,d,j] * G[i*8+j][o*16+d] ----------------
__global__ __launch_bounds__(256) void k_WG(const float* __restrict__ W,
                                            const float* __restrict__ Gp,
                                            float* __restrict__ agree) {
  int idx = blockIdx.x * 256 + threadIdx.x;  // over II*OO = 11520
  if (idx >= II * OO) return;
  int i = idx / OO, o = idx - (idx / OO) * OO;
  const float* wp = &W[(size_t)idx * 128];   // W[i][o][d][j], 16x8
  float acc = 0.f;
#pragma unroll
  for (int j = 0; j < 8; ++j) {
    const float* g0 = &Gp[(size_t)(i * 8 + j) * OD + o * 16];
    const float* g1 = g0 + (size_t)KK * OD;
#pragma unroll
    for (int d4 = 0; d4 < 4; ++d4) {
      float4 ga = *(const float4*)&g0[d4 * 4];
      float4 gb = *(const float4*)&g1[d4 * 4];
      acc = fmaf(wp[(d4 * 4 + 0) * 8 + j], ga.x + gb.x, acc);
      acc = fmaf(wp[(d4 * 4 + 1) * 8 + j], ga.y + gb.y, acc);
      acc = fmaf(wp[(d4 * 4 + 2) * 8 + j], ga.z + gb.z, acc);
      acc = fmaf(wp[(d4 * 4 + 3) * 8 + j], ga.w + gb.w, acc);
    }
  }
  agree[idx] = acc * (1.0f / (float)BB);
}

extern "C" void kernel_launch(void* const* d_in, const int* in_sizes, int n_in,
                              void* d_out, int out_size, void* d_ws, size_t ws_size,
                              hipStream_t stream) {
  const float* x = (const float*)d_in[0];   // [512][1152][8]
  const float* W = (const float*)d_in[1];   // [1152][10][16][8]
  float* out = (float*)d_out;               // [512][10][16][1] == flat v
  float* ws = (float*)d_ws;

  float* b_ij  = ws;                        // 11520
  float* c     = ws + 11520;                // 11520
  float* agree = ws + 23040;                // 11520
  float* sp    = ws + 34560;                // 72*81920 = 5898240 (aliased by Gp)
  float* Gp    = sp;                        // 2*9216*160 = 2949120 <= 5898240
  float* xT    = ws + 5932800;              // 9216*512 = 4718592
  float* vv    = ws + 10651392;             // 81920

  hipMemsetAsync(b_ij, 0, 11520 * sizeof(float), stream);
  k_transpose<<<dim3(288, 16), 256, 0, stream>>>(x, xT);
  k_softmax<<<OO, 256, 0, stream>>>(b_ij, c);   // uniform c from zeros

  for (int it = 0; it < 3; ++it) {
    k_s_part<<<dim3(NBT, NS), 256, 0, stream>>>(xT, W, c, sp);
    k_squash<<<320, 256, 0, stream>>>(sp, it == 2 ? out : vv);
    if (it < 2) {
      k_G<<<dim3(144, 2), 256, 0, stream>>>(xT, vv, Gp);
      k_WG<<<45, 256, 0, stream>>>(W, Gp, agree);
      k_bupd_softmax<<<OO, 256, 0, stream>>>(b_ij, agree, c);
    }
  }
}